// Round 7
// baseline (325.511 us; speedup 1.0000x reference)
//
#include <hip/hip_runtime.h>

#define B 8
#define K 16
#define H 224
#define W 224
#define PH 232
#define PW 232
#define WIN 9
#define NP (B * H * W)            // 401408 pixels

typedef float vf4a __attribute__((ext_vector_type(4)));
typedef const __attribute__((address_space(1))) char gchar;
typedef __attribute__((address_space(3))) char lchar;

// ---------------- Kernel M: weight via LDS DMA triple-buffer ----------------
// Block: 256 thr = q(8) x kg(4) x rr(8 rows); tile = 8 out-rows x 32 px x 16 k.
// Thread: 4 px x 4 k x 1 out-row.
// R4/R5 lesson: weight (HBM-latency) can't be latency-covered by VGPR
// prefetch (R4: 12 serialized ~1060cy loads/iter; R5: regalloc spilled the
// ping-pong). Fix: stage weight into LDS with global_load_lds (no VGPR cost),
// triple-buffered, one __syncthreads per iter (stage m+1 flies during
// consume m). Padded is read DIRECT from global: 27 MB total, L2-resident
// per XCD, ~10x L1 reuse -> short-latency loads that 16 waves/CU can hide.
//
// Weight LDS layout: wlds[3 buf][3 chunk][256 slot][float4]. Slot s holds
// chunks of pixel pi = s ^ ((s>>3)&3)  (global pre-swizzle, LDS linear:
// consumer ds_read_b128 for (p,t) then spans all 8 4-bank groups -> 2-way
// worst = free; kg lanes same-address broadcast). Chunk t of px P covers
// floats [(81P+9m)&~3 + 4t ..+3]; consumer rotation rot=(P+m)&3=(p+m)&3,
// compile-time after unroll. Bounds: max staged float idx = 81*NP-1 (exact
// last element); base >= 0 and 16B-aligned by construction.

__global__ __launch_bounds__(256, 4) void ncuts_dw(
    const float* __restrict__ seg,
    const float* __restrict__ padded,
    const float* __restrict__ weight,
    const float* __restrict__ sumw,
    float* __restrict__ ws)
{
    __shared__ float wlds[3][3][256][4];      // 36.9 KB
    __shared__ float red[4][16][2];

    const int tid = threadIdx.x;
    const int bid = blockIdx.x;               // b + 8*(wt + 7*ht)
    const int b   = bid & 7;                  // XCD x owns batch b
    const int rest = bid >> 3;                // 0..195
    const int ht  = rest / 7;
    const int wt  = rest - ht * 7;
    const int h0 = ht * 8, w0 = wt * 32;

    // ---- staging role: this thread fills slot tid with pixel pi's chunks ----
    const int pi = tid ^ ((tid >> 3) & 3);    // sigma(s): involution on p-bits
    const int rs = pi >> 5;                   // local row of staged pixel
    const int cs = pi & 31;                   // local col of staged pixel
    const long Pg = (long)(b * H + h0 + rs) * W + w0 + cs;
    const float* wgb = weight + 81 * Pg;

    // ---- compute role ----
    const int lane = tid & 63;
    const int q    = lane & 7;                // px group (4 px)
    const int kg   = (lane >> 3) & 3;         // k quad
    const int rr   = tid >> 5;                // 0..7 out-row
    const int xq   = (q >> 1) & 3;            // consumer-side swizzle constant
    const int h    = h0 + rr;
    const long pix0 = (long)(b * H + h) * W + w0 + 4 * q;

    const float* pb[4];
#pragma unroll
    for (int kk = 0; kk < 4; ++kk)
        pb[kk] = padded + ((long)(b * K + kg * 4 + kk) * PH + (h0 + rr)) * PW
                 + w0 + 4 * q;

    float acc[4][4];                          // [kk][p]
#pragma unroll
    for (int kk = 0; kk < 4; ++kk)
#pragma unroll
        for (int p = 0; p < 4; ++p) acc[kk][p] = 0.f;

    // prologue: stage m=0 into buf 0
    {
        const int offf = -(cs & 3);           // 9*0 - ((cs+0)&3)
        const gchar* g0 = (const gchar*)(wgb + offf);
        lchar* l0 = (lchar*)&wlds[0][0][tid & 192][0];
        __builtin_amdgcn_global_load_lds(g0,      l0,        16, 0, 0);
        __builtin_amdgcn_global_load_lds(g0 + 16, l0 + 4096, 16, 0, 0);
        __builtin_amdgcn_global_load_lds(g0 + 32, l0 + 8192, 16, 0, 0);
    }

#pragma unroll
    for (int m = 0; m < 9; ++m) {
        const int buf = m % 3;
        __syncthreads();                      // stage(m) landed (issued 1 iter ago)
        if (m < 8) {                          // stage(m+1): flies during consume(m)
            const int nb = (m + 1) % 3;
            const int offf = 9 * (m + 1) - ((cs + m + 1) & 3);
            const gchar* g0 = (const gchar*)(wgb + offf);
            lchar* l0 = (lchar*)&wlds[nb][0][tid & 192][0];
            __builtin_amdgcn_global_load_lds(g0,      l0,        16, 0, 0);
            __builtin_amdgcn_global_load_lds(g0 + 16, l0 + 4096, 16, 0, 0);
            __builtin_amdgcn_global_load_lds(g0 + 32, l0 + 8192, 16, 0, 0);
        }
        // padded window rows: 12 direct global loads (L1/L2-hot)
        float win[4][12];
#pragma unroll
        for (int kk = 0; kk < 4; ++kk) {
            const float* lb = pb[kk] + m * PW;
            vf4a a0 = *(const vf4a*)lb;
            vf4a a1 = *(const vf4a*)(lb + 4);
            vf4a a2 = *(const vf4a*)(lb + 8);
#pragma unroll
            for (int t = 0; t < 4; ++t) {
                win[kk][t]     = ((const float*)&a0)[t];
                win[kk][t + 4] = ((const float*)&a1)[t];
                win[kk][t + 8] = ((const float*)&a2)[t];
            }
        }
        // weight from LDS: per px p, 3 ds_read_b128 -> 36 FMAs
#pragma unroll
        for (int p = 0; p < 4; ++p) {
            const int rot = (p + m) & 3;
            const int sp  = rr * 32 + 4 * q + (p ^ xq);
            vf4a c0 = *(const vf4a*)&wlds[buf][0][sp][0];
            vf4a c1 = *(const vf4a*)&wlds[buf][1][sp][0];
            vf4a c2 = *(const vf4a*)&wlds[buf][2][sp][0];
            float wk[12];
#pragma unroll
            for (int t = 0; t < 4; ++t) {
                wk[t]     = ((const float*)&c0)[t];
                wk[t + 4] = ((const float*)&c1)[t];
                wk[t + 8] = ((const float*)&c2)[t];
            }
#pragma unroll
            for (int kk = 0; kk < 4; ++kk)
#pragma unroll
                for (int n = 0; n < 9; ++n)
                    acc[kk][p] = fmaf(win[kk][p + n], wk[rot + n], acc[kk][p]);
        }
    }

    // ---- epilogue: assocA/assocV partials (1 row, 4 px, 4 k) ----
    float aA[4], aV[4];
    {
        const vf4a sw4 = __builtin_nontemporal_load((const vf4a*)(sumw + pix0));
#pragma unroll
        for (int kk = 0; kk < 4; ++kk) {
            const int k = kg * 4 + kk;
            const float* sp = seg + ((long)(b * K + k) * H + h) * W + w0 + 4 * q;
            const vf4a s4 = __builtin_nontemporal_load((const vf4a*)sp);
            float a = 0.f, v = 0.f;
#pragma unroll
            for (int p = 0; p < 4; ++p) {
                a = fmaf(acc[kk][p], ((const float*)&s4)[p], a);
                v = fmaf(((const float*)&sw4)[p], ((const float*)&s4)[p], v);
            }
            aA[kk] = a; aV[kk] = v;
        }
    }
    // reduce over q (lane bits 0-2) and row-parity (bit 5); kg lanes survive
#pragma unroll
    for (int off = 0; off < 4; ++off) {
        const int d = (off < 3) ? (1 << off) : 32;
#pragma unroll
        for (int kk = 0; kk < 4; ++kk) {
            aA[kk] += __shfl_xor(aA[kk], d);
            aV[kk] += __shfl_xor(aV[kk], d);
        }
    }
    const int wv = tid >> 6;
    if ((lane & 39) == 0) {                   // lanes 0,8,16,24
#pragma unroll
        for (int kk = 0; kk < 4; ++kk) {
            red[wv][kg * 4 + kk][0] = aA[kk];
            red[wv][kg * 4 + kk][1] = aV[kk];
        }
    }
    __syncthreads();
    if (tid < 32) {
        const int k  = tid >> 1;
        const int ab = tid & 1;
        const float v = red[0][k][ab] + red[1][k][ab] + red[2][k][ab] + red[3][k][ab];
        atomicAdd(&ws[ab * 128 + b * 16 + k], v);
    }
}

__global__ void ncuts_final(const float* __restrict__ ws,
                            const int* __restrict__ ncut_k,
                            float* __restrict__ out)
{
    const int t = threadIdx.x;          // 128 threads: t = b*16 + k
    const int b = t >> 4;
    const int k = t & 15;
    float r = ws[b * K + k] / ws[128 + b * K + k];
#pragma unroll
    for (int off = 1; off < 16; off <<= 1) r += __shfl_xor(r, off, 16);
    if (k == 0) out[b] = (float)(*ncut_k) - r;
}

extern "C" void kernel_launch(void* const* d_in, const int* in_sizes, int n_in,
                              void* d_out, int out_size, void* d_ws, size_t ws_size,
                              hipStream_t stream) {
    (void)in_sizes; (void)n_in; (void)out_size; (void)ws_size;
    const float* seg    = (const float*)d_in[0];
    const float* padded = (const float*)d_in[1];
    const float* weight = (const float*)d_in[2];
    const float* sumw   = (const float*)d_in[3];
    const int*   nk     = (const int*)d_in[5];
    float* ws  = (float*)d_ws;
    float* out = (float*)d_out;

    hipMemsetAsync(ws, 0, 2 * B * K * sizeof(float), stream);
    ncuts_dw<<<8 * 28 * 7, 256, 0, stream>>>(seg, padded, weight, sumw, ws);
    ncuts_final<<<1, 128, 0, stream>>>(ws, nk, out);
}

// Round 8
// 243.700 us; speedup vs baseline: 1.3357x; 1.3357x over previous
//
#include <hip/hip_runtime.h>

#define B 8
#define K 16
#define H 224
#define W 224
#define PH 232
#define PW 232
#define NP (B * H * W)            // 401408 pixels

typedef float vf4a __attribute__((ext_vector_type(4)));
typedef const __attribute__((address_space(1))) char gchar;
typedef __attribute__((address_space(3))) char lchar;

// ---------------- Kernel F: fused transpose-in-LDS direct kernel ----------------
// Tile: 4 out-rows x 32 px x 16 k; grid 3136 = 8b x 56ht x 7wt (b = XCD).
// Weight staged WHOLE-TILE, coalesced: 4 row-runs, each 32px x 81 floats =
// 10368B CONTIGUOUS in native [pix][81] layout -> global_load_lds with
// linear src AND linear dest (the DMA's ideal case; R7's scatter-DMA is the
// anti-case). One barrier total; compute is barrier-free straight-line code.
// Wave w (of 4) owns out-row w. mm loop = tap row = loop constant, so the
// aligned-window rotation rot=(p+mm)&3 is compile-time (no runtime indexing).
// Weight consumed from LDS: per (px,mm) 3 ds_read_b128 (12-float aligned
// window); q-lanes land on 8 distinct bank-quads (324 floats/px => granule
// stride 81 == 1 mod 8), kg-lanes broadcast -> conflict-free.
// Padded read DIRECT from global: 30.7KB/block unique, ~2.9MB/XCD resident
// -> L2-hot; 6 independent loads/iter pipelined by the scheduler across the
// fully-unrolled mm iterations (no #pragma unroll 1 to block it: R4 lesson).
// LDS 42KB static -> 3 blocks/CU; cross-block phase interleave covers staging.

__global__ __launch_bounds__(256, 3) void ncuts_f(
    const float* __restrict__ seg,
    const float* __restrict__ padded,
    const float* __restrict__ weight,
    const float* __restrict__ sumw,
    float* __restrict__ ws)
{
    __shared__ __align__(16) float wlds[4 * 2592];   // 41.5 KB
    __shared__ float red[4][16][2];

    const int tid = threadIdx.x;
    const int bid = blockIdx.x;               // b + 8*(wt + 7*ht)
    const int b    = bid & 7;                 // XCD x owns batch b
    const int rest = bid >> 3;                // 0..391
    const int ht = rest / 7;                  // 0..55
    const int wt = rest - ht * 7;             // 0..6
    const int h0 = ht * 4, w0 = wt * 32;

    // ---- stage weight tile: 4 runs x 648 float4, contiguous + coalesced ----
    {
        const int wv64 = tid & 192;           // wave-uniform slot base
#pragma unroll
        for (int ro = 0; ro < 4; ++ro) {
            const gchar* gsrc = (const gchar*)(weight
                + 81L * (((long)(b * H + h0 + ro)) * W + w0)) + (long)tid * 16;
            lchar* ldst = (lchar*)&wlds[ro * 2592] + wv64 * 16;
            __builtin_amdgcn_global_load_lds(gsrc,        ldst,        16, 0, 0);
            __builtin_amdgcn_global_load_lds(gsrc + 4096, ldst + 4096, 16, 0, 0);
            if (tid < 136)                    // tail: slots 512..647
                __builtin_amdgcn_global_load_lds(gsrc + 8192, ldst + 8192, 16, 0, 0);
        }
    }
    __syncthreads();                          // single barrier of the kernel

    const int lane = tid & 63;
    const int q  = lane & 7;                  // px group (4 px)
    const int kg = lane >> 3;                 // 0..7 -> k pair
    const int r  = tid >> 6;                  // wave id = out-row 0..3
    const int h  = h0 + r;
    const long pix0 = ((long)(b * H + h)) * W + w0 + 4 * q;

    const float* pb0 = padded + (((long)(b * K + kg * 2 + 0)) * PH + h) * PW + w0 + 4 * q;
    const float* pb1 = padded + (((long)(b * K + kg * 2 + 1)) * PH + h) * PW + w0 + 4 * q;
    const float* wq  = &wlds[r * 2592 + 324 * q];   // this thread's 4-px weight base

    float acc[2][4];                          // [kk][p]
#pragma unroll
    for (int kk = 0; kk < 2; ++kk)
#pragma unroll
        for (int p = 0; p < 4; ++p) acc[kk][p] = 0.f;

#pragma unroll
    for (int mm = 0; mm < 9; ++mm) {          // tap row m = mm (compile-time)
        // padded windows, 2 k-planes: 12 floats each (direct global, L2-hot)
        float k0[12], k1[12];
        {
            const float* a = pb0 + mm * PW;
            vf4a x = *(const vf4a*)a, y = *(const vf4a*)(a + 4), z = *(const vf4a*)(a + 8);
#pragma unroll
            for (int t = 0; t < 4; ++t) {
                k0[t] = ((const float*)&x)[t];
                k0[t + 4] = ((const float*)&y)[t];
                k0[t + 8] = ((const float*)&z)[t];
            }
        }
        {
            const float* a = pb1 + mm * PW;
            vf4a x = *(const vf4a*)a, y = *(const vf4a*)(a + 4), z = *(const vf4a*)(a + 8);
#pragma unroll
            for (int t = 0; t < 4; ++t) {
                k1[t] = ((const float*)&x)[t];
                k1[t + 4] = ((const float*)&y)[t];
                k1[t + 8] = ((const float*)&z)[t];
            }
        }
        // weight windows: per px, 12-float aligned window (3 ds_read_b128)
        float ww[4][12];
#pragma unroll
        for (int p = 0; p < 4; ++p) {
            const int base = 81 * p + 9 * mm - ((p + mm) & 3);  // 16B-aligned
            vf4a x = *(const vf4a*)(wq + base);
            vf4a y = *(const vf4a*)(wq + base + 4);
            vf4a z = *(const vf4a*)(wq + base + 8);
#pragma unroll
            for (int t = 0; t < 4; ++t) {
                ww[p][t] = ((const float*)&x)[t];
                ww[p][t + 4] = ((const float*)&y)[t];
                ww[p][t + 8] = ((const float*)&z)[t];
            }
        }
        // 72 FMAs, all-static indexing
#pragma unroll
        for (int n = 0; n < 9; ++n)
#pragma unroll
            for (int p = 0; p < 4; ++p) {
                acc[0][p] = fmaf(k0[p + n], ww[p][((p + mm) & 3) + n], acc[0][p]);
                acc[1][p] = fmaf(k1[p + n], ww[p][((p + mm) & 3) + n], acc[1][p]);
            }
    }

    // ---- epilogue: assocA/assocV partials (1 row, 4 px, 2 k) ----
    float aA[2], aV[2];
    {
        const vf4a sw4 = __builtin_nontemporal_load((const vf4a*)(sumw + pix0));
#pragma unroll
        for (int kk = 0; kk < 2; ++kk) {
            const int k = kg * 2 + kk;
            const float* sp = seg + (((long)(b * K + k)) * H + h) * W + w0 + 4 * q;
            const vf4a s4 = __builtin_nontemporal_load((const vf4a*)sp);
            float a = 0.f, v = 0.f;
#pragma unroll
            for (int p = 0; p < 4; ++p) {
                a = fmaf(acc[kk][p], ((const float*)&s4)[p], a);
                v = fmaf(((const float*)&sw4)[p], ((const float*)&s4)[p], v);
            }
            aA[kk] = a; aV[kk] = v;
        }
    }
    // reduce over q (lane bits 0-2); kg lanes survive
#pragma unroll
    for (int d = 1; d <= 4; d <<= 1) {
#pragma unroll
        for (int kk = 0; kk < 2; ++kk) {
            aA[kk] += __shfl_xor(aA[kk], d);
            aV[kk] += __shfl_xor(aV[kk], d);
        }
    }
    if (q == 0) {                             // 8 lanes per wave
#pragma unroll
        for (int kk = 0; kk < 2; ++kk) {
            red[r][kg * 2 + kk][0] = aA[kk];
            red[r][kg * 2 + kk][1] = aV[kk];
        }
    }
    __syncthreads();
    if (tid < 32) {
        const int k  = tid >> 1;
        const int ab = tid & 1;
        const float v = red[0][k][ab] + red[1][k][ab] + red[2][k][ab] + red[3][k][ab];
        atomicAdd(&ws[ab * 128 + b * 16 + k], v);
    }
}

__global__ void ncuts_final(const float* __restrict__ ws,
                            const int* __restrict__ ncut_k,
                            float* __restrict__ out)
{
    const int t = threadIdx.x;          // 128 threads: t = b*16 + k
    const int b = t >> 4;
    const int k = t & 15;
    float r = ws[b * K + k] / ws[128 + b * K + k];
#pragma unroll
    for (int off = 1; off < 16; off <<= 1) r += __shfl_xor(r, off, 16);
    if (k == 0) out[b] = (float)(*ncut_k) - r;
}

extern "C" void kernel_launch(void* const* d_in, const int* in_sizes, int n_in,
                              void* d_out, int out_size, void* d_ws, size_t ws_size,
                              hipStream_t stream) {
    (void)in_sizes; (void)n_in; (void)out_size; (void)ws_size;
    const float* seg    = (const float*)d_in[0];
    const float* padded = (const float*)d_in[1];
    const float* weight = (const float*)d_in[2];
    const float* sumw   = (const float*)d_in[3];
    const int*   nk     = (const int*)d_in[5];
    float* ws  = (float*)d_ws;
    float* out = (float*)d_out;

    hipMemsetAsync(ws, 0, 2 * B * K * sizeof(float), stream);
    ncuts_f<<<8 * 56 * 7, 256, 0, stream>>>(seg, padded, weight, sumw, ws);
    ncuts_final<<<1, 128, 0, stream>>>(ws, nk, out);
}

// Round 9
// 237.179 us; speedup vs baseline: 1.3724x; 1.0275x over previous
//
#include <hip/hip_runtime.h>

#define B 8
#define K 16
#define H 224
#define W 224
#define PH 232
#define PW 232
#define NP (B * H * W)            // 401408 pixels

typedef float vf4a __attribute__((ext_vector_type(4)));
typedef const __attribute__((address_space(1))) char gchar;
typedef __attribute__((address_space(3))) char lchar;

// ---------------- Kernel F2: fused transpose-in-LDS + padded reg ping-pong ----
// R8 base (84.8us, VGPR 72): fused weight staging is right; remaining stall is
// the per-iteration global padded load->use chain (compiler sank loads next to
// uses at minimal pressure). Fix: explicit 6xvf4a ping-pong prefetch of the
// NEXT iteration's padded windows, pinned above the current FMAs by
// sched_barrier(0). Only 48 prefetch regs (vs R5's 96-reg weight ping-pong
// that spilled); FMA operands index the buffer granules directly (static
// (p+n)>>2, no copy arrays).
// Tile: 4 out-rows x 32 px x 16 k; grid 3136 = 8b x 56ht x 7wt (b = XCD).
// Weight staged whole-tile via global_load_lds, linear src+dst, coalesced.
// Weight consumed from LDS: per (px,mm) 3 ds_read_b128, 16B-aligned window
// with compile-time rotation; q-lanes hit 8 distinct bank-quads (conflict-free,
// measured 0). One barrier total.

#define LOADP(dst, mm_) do {                                                 \
    const float* a0_ = pb0 + (mm_) * PW;                                     \
    const float* a1_ = pb1 + (mm_) * PW;                                     \
    dst[0] = *(const vf4a*)a0_;                                              \
    dst[1] = *(const vf4a*)(a0_ + 4);                                        \
    dst[2] = *(const vf4a*)(a0_ + 8);                                        \
    dst[3] = *(const vf4a*)a1_;                                              \
    dst[4] = *(const vf4a*)(a1_ + 4);                                        \
    dst[5] = *(const vf4a*)(a1_ + 8);                                        \
} while (0)

#define CONSUME(src, mm_) do {                                               \
    float ww_[4][12];                                                        \
    _Pragma("unroll")                                                        \
    for (int p = 0; p < 4; ++p) {                                            \
        const int base = 81 * p + 9 * (mm_) - ((p + (mm_)) & 3);             \
        vf4a x = *(const vf4a*)(wq + base);                                  \
        vf4a y = *(const vf4a*)(wq + base + 4);                              \
        vf4a z = *(const vf4a*)(wq + base + 8);                              \
        _Pragma("unroll")                                                    \
        for (int t = 0; t < 4; ++t) {                                        \
            ww_[p][t]     = ((const float*)&x)[t];                           \
            ww_[p][t + 4] = ((const float*)&y)[t];                           \
            ww_[p][t + 8] = ((const float*)&z)[t];                           \
        }                                                                    \
    }                                                                        \
    _Pragma("unroll")                                                        \
    for (int n = 0; n < 9; ++n)                                              \
        _Pragma("unroll")                                                    \
        for (int p = 0; p < 4; ++p) {                                        \
            const int rot = (p + (mm_)) & 3;                                 \
            const int g = (p + n) >> 2, e = (p + n) & 3;                     \
            acc[0][p] = fmaf(((const float*)&src[g])[e],                     \
                             ww_[p][rot + n], acc[0][p]);                    \
            acc[1][p] = fmaf(((const float*)&src[3 + g])[e],                 \
                             ww_[p][rot + n], acc[1][p]);                    \
        }                                                                    \
} while (0)

__global__ __launch_bounds__(256, 3) void ncuts_f(
    const float* __restrict__ seg,
    const float* __restrict__ padded,
    const float* __restrict__ weight,
    const float* __restrict__ sumw,
    float* __restrict__ ws)
{
    __shared__ __align__(16) float wlds[4 * 2592];   // 41.5 KB
    __shared__ float red[4][16][2];

    const int tid = threadIdx.x;
    const int bid = blockIdx.x;               // b + 8*(wt + 7*ht)
    const int b    = bid & 7;                 // XCD x owns batch b
    const int rest = bid >> 3;                // 0..391
    const int ht = rest / 7;                  // 0..55
    const int wt = rest - ht * 7;             // 0..6
    const int h0 = ht * 4, w0 = wt * 32;

    // ---- stage weight tile: 4 runs x 648 float4, contiguous + coalesced ----
    {
        const int wv64 = tid & 192;           // wave-uniform slot base
#pragma unroll
        for (int ro = 0; ro < 4; ++ro) {
            const gchar* gsrc = (const gchar*)(weight
                + 81L * (((long)(b * H + h0 + ro)) * W + w0)) + (long)tid * 16;
            lchar* ldst = (lchar*)&wlds[ro * 2592] + wv64 * 16;
            __builtin_amdgcn_global_load_lds(gsrc,        ldst,        16, 0, 0);
            __builtin_amdgcn_global_load_lds(gsrc + 4096, ldst + 4096, 16, 0, 0);
            if (tid < 136)                    // tail: slots 512..647
                __builtin_amdgcn_global_load_lds(gsrc + 8192, ldst + 8192, 16, 0, 0);
        }
    }
    __syncthreads();                          // single barrier of the kernel

    const int lane = tid & 63;
    const int q  = lane & 7;                  // px group (4 px)
    const int kg = lane >> 3;                 // 0..7 -> k pair
    const int r  = tid >> 6;                  // wave id = out-row 0..3
    const int h  = h0 + r;
    const long pix0 = ((long)(b * H + h)) * W + w0 + 4 * q;

    const float* pb0 = padded + (((long)(b * K + kg * 2 + 0)) * PH + h) * PW + w0 + 4 * q;
    const float* pb1 = padded + (((long)(b * K + kg * 2 + 1)) * PH + h) * PW + w0 + 4 * q;
    const float* wq  = &wlds[r * 2592 + 324 * q];   // this thread's 4-px weight base

    float acc[2][4];                          // [kk][p]
#pragma unroll
    for (int kk = 0; kk < 2; ++kk)
#pragma unroll
        for (int p = 0; p < 4; ++p) acc[kk][p] = 0.f;

    vf4a bufA[6], bufB[6];                    // padded ping-pong (24+24 VGPR)
    LOADP(bufA, 0);
#pragma unroll
    for (int mm = 0; mm < 9; ++mm) {          // mm compile-time after unroll
        if (mm < 8) {                         // prefetch padded for mm+1
            if (mm & 1) LOADP(bufA, mm + 1);
            else        LOADP(bufB, mm + 1);
        }
        __builtin_amdgcn_sched_barrier(0);    // pin prefetch above the FMAs
        if (mm & 1) CONSUME(bufB, mm);
        else        CONSUME(bufA, mm);
    }

    // ---- epilogue: assocA/assocV partials (1 row, 4 px, 2 k) ----
    float aA[2], aV[2];
    {
        const vf4a sw4 = __builtin_nontemporal_load((const vf4a*)(sumw + pix0));
#pragma unroll
        for (int kk = 0; kk < 2; ++kk) {
            const int k = kg * 2 + kk;
            const float* sp = seg + (((long)(b * K + k)) * H + h) * W + w0 + 4 * q;
            const vf4a s4 = __builtin_nontemporal_load((const vf4a*)sp);
            float a = 0.f, v = 0.f;
#pragma unroll
            for (int p = 0; p < 4; ++p) {
                a = fmaf(acc[kk][p], ((const float*)&s4)[p], a);
                v = fmaf(((const float*)&sw4)[p], ((const float*)&s4)[p], v);
            }
            aA[kk] = a; aV[kk] = v;
        }
    }
    // reduce over q (lane bits 0-2); kg lanes survive
#pragma unroll
    for (int d = 1; d <= 4; d <<= 1) {
#pragma unroll
        for (int kk = 0; kk < 2; ++kk) {
            aA[kk] += __shfl_xor(aA[kk], d);
            aV[kk] += __shfl_xor(aV[kk], d);
        }
    }
    if (q == 0) {                             // 8 lanes per wave
#pragma unroll
        for (int kk = 0; kk < 2; ++kk) {
            red[r][kg * 2 + kk][0] = aA[kk];
            red[r][kg * 2 + kk][1] = aV[kk];
        }
    }
    __syncthreads();
    if (tid < 32) {
        const int k  = tid >> 1;
        const int ab = tid & 1;
        const float v = red[0][k][ab] + red[1][k][ab] + red[2][k][ab] + red[3][k][ab];
        atomicAdd(&ws[ab * 128 + b * 16 + k], v);
    }
}

__global__ void ncuts_final(const float* __restrict__ ws,
                            const int* __restrict__ ncut_k,
                            float* __restrict__ out)
{
    const int t = threadIdx.x;          // 128 threads: t = b*16 + k
    const int b = t >> 4;
    const int k = t & 15;
    float r = ws[b * K + k] / ws[128 + b * K + k];
#pragma unroll
    for (int off = 1; off < 16; off <<= 1) r += __shfl_xor(r, off, 16);
    if (k == 0) out[b] = (float)(*ncut_k) - r;
}

extern "C" void kernel_launch(void* const* d_in, const int* in_sizes, int n_in,
                              void* d_out, int out_size, void* d_ws, size_t ws_size,
                              hipStream_t stream) {
    (void)in_sizes; (void)n_in; (void)out_size; (void)ws_size;
    const float* seg    = (const float*)d_in[0];
    const float* padded = (const float*)d_in[1];
    const float* weight = (const float*)d_in[2];
    const float* sumw   = (const float*)d_in[3];
    const int*   nk     = (const int*)d_in[5];
    float* ws  = (float*)d_ws;
    float* out = (float*)d_out;

    hipMemsetAsync(ws, 0, 2 * B * K * sizeof(float), stream);
    ncuts_f<<<8 * 56 * 7, 256, 0, stream>>>(seg, padded, weight, sumw, ws);
    ncuts_final<<<1, 128, 0, stream>>>(ws, nk, out);
}